// Round 2
// baseline (87.945 us; speedup 1.0000x reference)
//
#include <hip/hip_runtime.h>

// CenterLoss fused: B=2048, C=16384, D=2048.
// Only distmat[b, labels[b]] survives into the loss, so compute
// ||x_b - centers[l_b]||^2 = x_sq + c_sq - 2*dot per row (same algebra as
// reference), then the LAST block (ticket counter) reduces the mean in-kernel.
// ws layout: [0, 8192) = float dist[2048]; [8192, 8196) = uint ticket counter.

#define FEAT_DIM 2048
#define BATCH 2048

__global__ __launch_bounds__(256) void center_loss_fused(
    const float* __restrict__ x,
    const int* __restrict__ labels,
    const float* __restrict__ centers,
    float* __restrict__ out,
    float* __restrict__ dist_ws,
    unsigned int* __restrict__ counter) {
    const int b = blockIdx.x;
    const int lbl = labels[b];
    const float4* xr = reinterpret_cast<const float4*>(x + (size_t)b * FEAT_DIM);
    const float4* cr = reinterpret_cast<const float4*>(centers + (size_t)lbl * FEAT_DIM);

    float sx2 = 0.f, sc2 = 0.f, sxc = 0.f;
    #pragma unroll
    for (int it = 0; it < (FEAT_DIM / 4) / 256; ++it) {  // 2 iters
        const int i = threadIdx.x + it * 256;
        float4 xv = xr[i];
        float4 cv = cr[i];
        sx2 += xv.x * xv.x + xv.y * xv.y + xv.z * xv.z + xv.w * xv.w;
        sc2 += cv.x * cv.x + cv.y * cv.y + cv.z * cv.z + cv.w * cv.w;
        sxc += xv.x * cv.x + xv.y * cv.y + xv.z * cv.z + xv.w * cv.w;
    }

    // intra-wave reduce (wave = 64)
    #pragma unroll
    for (int off = 32; off > 0; off >>= 1) {
        sx2 += __shfl_down(sx2, off, 64);
        sc2 += __shfl_down(sc2, off, 64);
        sxc += __shfl_down(sxc, off, 64);
    }

    __shared__ float red[3][4];
    __shared__ unsigned int s_ticket;
    const int wave = threadIdx.x >> 6;
    const int lane = threadIdx.x & 63;
    if (lane == 0) {
        red[0][wave] = sx2;
        red[1][wave] = sc2;
        red[2][wave] = sxc;
    }
    __syncthreads();

    if (threadIdx.x == 0) {
        float tx2 = red[0][0] + red[0][1] + red[0][2] + red[0][3];
        float tc2 = red[1][0] + red[1][1] + red[1][2] + red[1][3];
        float txc = red[2][0] + red[2][1] + red[2][2] + red[2][3];
        float d = tx2 + tc2 - 2.0f * txc;
        d = fminf(fmaxf(d, 1e-12f), 1e12f);  // clip like reference
        // L2-coherent store so the last block can read it past its own L1
        __hip_atomic_store(&dist_ws[b], d, __ATOMIC_RELAXED,
                           __HIP_MEMORY_SCOPE_AGENT);
        __threadfence();  // release: dist store visible before ticket inc
        s_ticket = atomicAdd(counter, 1u);
        __threadfence();  // acquire side for the final reduction reads
    }
    __syncthreads();  // broadcast s_ticket (block-uniform branch below)

    if (s_ticket == BATCH - 1) {
        // last block: all 2048 dists are in L2; fixed-order deterministic mean
        float s = 0.f;
        for (int i = threadIdx.x; i < BATCH; i += 256)
            s += __hip_atomic_load(&dist_ws[i], __ATOMIC_RELAXED,
                                   __HIP_MEMORY_SCOPE_AGENT);
        #pragma unroll
        for (int off = 32; off > 0; off >>= 1) s += __shfl_down(s, off, 64);
        __shared__ float red2[4];
        if (lane == 0) red2[wave] = s;
        __syncthreads();
        if (threadIdx.x == 0)
            out[0] = (red2[0] + red2[1] + red2[2] + red2[3]) / (float)BATCH;
    }
}

extern "C" void kernel_launch(void* const* d_in, const int* in_sizes, int n_in,
                              void* d_out, int out_size, void* d_ws, size_t ws_size,
                              hipStream_t stream) {
    const float* x = (const float*)d_in[0];
    const int* labels = (const int*)d_in[1];
    const float* centers = (const float*)d_in[2];
    float* out = (float*)d_out;
    float* dist_ws = (float*)d_ws;                          // BATCH floats
    unsigned int* counter =
        (unsigned int*)((char*)d_ws + (size_t)BATCH * 4);   // 1 uint

    // ticket counter must be 0 at every launch (ws is poisoned once, and the
    // kernel leaves it at BATCH) — cheap 4-byte memset node in the graph.
    hipMemsetAsync(counter, 0, sizeof(unsigned int), stream);
    center_loss_fused<<<BATCH, 256, 0, stream>>>(x, labels, centers, out,
                                                 dist_ws, counter);
}

// Round 3
// 11.471 us; speedup vs baseline: 7.6666x; 7.6666x over previous
//
#include <hip/hip_runtime.h>

// CenterLoss: B=2048, C=16384, D=2048.
// Only distmat[b, labels[b]] survives => per row compute
// x_sq + c_sq - 2*dot over the gathered center (same algebra as reference).
// Round-2 lesson: single-address atomic ticket across 2048 blocks serializes
// at ~58ns/op (120us) — stay with two dispatches, make them lean.
// Kernel 1: one WAVE per row (no LDS, no syncthreads), 512 blocks x 256 thr.
// Kernel 2: one wave, float4 loads, mean of 2048 dists.

#define FEAT_DIM 2048
#define BATCH 2048

__global__ __launch_bounds__(256) void center_dist_kernel(
    const float* __restrict__ x,
    const int* __restrict__ labels,
    const float* __restrict__ centers,
    float* __restrict__ dist_ws) {
    const int row  = blockIdx.x * 4 + (threadIdx.x >> 6);  // 4 waves/block
    const int lane = threadIdx.x & 63;
    const int lbl  = labels[row];
    const float4* xr = reinterpret_cast<const float4*>(x + (size_t)row * FEAT_DIM);
    const float4* cr = reinterpret_cast<const float4*>(centers + (size_t)lbl * FEAT_DIM);

    float sx2 = 0.f, sc2 = 0.f, sxc = 0.f;
    #pragma unroll
    for (int j = 0; j < (FEAT_DIM / 4) / 64; ++j) {  // 8 iters, 1KB/wave/iter
        float4 xv = xr[lane + 64 * j];
        float4 cv = cr[lane + 64 * j];
        sx2 += xv.x * xv.x + xv.y * xv.y + xv.z * xv.z + xv.w * xv.w;
        sc2 += cv.x * cv.x + cv.y * cv.y + cv.z * cv.z + cv.w * cv.w;
        sxc += xv.x * cv.x + xv.y * cv.y + xv.z * cv.z + xv.w * cv.w;
    }

    // intra-wave reduce (wave = 64 lanes) — no LDS, no block sync
    #pragma unroll
    for (int off = 32; off > 0; off >>= 1) {
        sx2 += __shfl_down(sx2, off, 64);
        sc2 += __shfl_down(sc2, off, 64);
        sxc += __shfl_down(sxc, off, 64);
    }

    if (lane == 0) {
        float d = sx2 + sc2 - 2.0f * sxc;
        d = fminf(fmaxf(d, 1e-12f), 1e12f);  // clip like reference
        dist_ws[row] = d;
    }
}

__global__ __launch_bounds__(64) void mean_kernel(
    const float* __restrict__ dist_ws, float* __restrict__ out) {
    const float4* dw = reinterpret_cast<const float4*>(dist_ws);  // 512 float4
    float s = 0.f;
    #pragma unroll
    for (int j = 0; j < (BATCH / 4) / 64; ++j) {  // 8 iters
        float4 v = dw[threadIdx.x + 64 * j];
        s += v.x + v.y + v.z + v.w;
    }
    #pragma unroll
    for (int off = 32; off > 0; off >>= 1) s += __shfl_down(s, off, 64);
    if (threadIdx.x == 0) out[0] = s / (float)BATCH;
}

extern "C" void kernel_launch(void* const* d_in, const int* in_sizes, int n_in,
                              void* d_out, int out_size, void* d_ws, size_t ws_size,
                              hipStream_t stream) {
    const float* x = (const float*)d_in[0];
    const int* labels = (const int*)d_in[1];
    const float* centers = (const float*)d_in[2];
    float* out = (float*)d_out;
    float* dist_ws = (float*)d_ws;  // BATCH floats

    center_dist_kernel<<<BATCH / 4, 256, 0, stream>>>(x, labels, centers, dist_ws);
    mean_kernel<<<1, 64, 0, stream>>>(dist_ws, out);
}